// Round 2
// baseline (9506.674 us; speedup 1.0000x reference)
//
#include <hip/hip_runtime.h>

typedef float2 cplx;

constexpr int B_   = 2;
constexpr int C_   = 12;
constexpr int NR   = 96;    // image rows
constexpr int NC_  = 96;    // cols
constexpr int NS   = 48;    // slices
constexpr int NP   = 288;   // padded rows
constexpr int NCOL = NC_ * NS;      // 4608 columns per row
constexpr int NVOX = NR * NCOL;     // 442368 voxels per batch
constexpr int TILE = 48;            // columns per K1/K3 block
constexpr int TILES = NCOL / TILE;  // 96
constexpr int LSTR = 49;            // padded nc-stride in K2 plane LDS
constexpr float PI2 = 6.28318530717958647692f;
constexpr float R96 = 1.f / 96.f, R48 = 1.f / 48.f, R288 = 1.f / 288.f;

// scalar workspace slots (floats)
#define SC_RTR   0
#define SC_PAP   2
#define SC_RTR1  4
#define SC_ALPHA 6
#define SC_BETA  8
#define SC_ACT   10

__device__ inline cplx cmulc(cplx a, cplx b){ return make_float2(a.x*b.x - a.y*b.y, a.x*b.y + a.y*b.x); }
__device__ inline cplx cmuljc(cplx a, cplx b){ return make_float2(a.x*b.x + a.y*b.y, a.y*b.x - a.x*b.y); } // a*conj(b)
__device__ inline cplx caddc(cplx a, cplx b){ return make_float2(a.x+b.x, a.y+b.y); }
__device__ inline cplx csubc(cplx a, cplx b){ return make_float2(a.x-b.x, a.y-b.y); }

__device__ inline void atomAddF(float* p, float v){
    __hip_atomic_fetch_add(p, v, __ATOMIC_RELAXED, __HIP_MEMORY_SCOPE_AGENT);
}

// e^{-2*pi*i * k * rN}
__device__ __forceinline__ cplx twf(float k, float rN){
    float s, c; __sincosf(-PI2 * k * rN, &s, &c);
    return make_float2(c, s);
}

// ---------------------------------------------------------------------------
// Register-level DFT cores. Internal twiddles are compile-time constants.
// ---------------------------------------------------------------------------
template<bool INV>
__device__ __forceinline__ cplx w16k(int k){  // W16^k = e^{-2pi i k/16} (conj if INV)
    constexpr float re[10] = {1.f, 0.92387953251f, 0.70710678119f, 0.38268343236f, 0.f,
                              -0.38268343236f, -0.70710678119f, -0.92387953251f, -1.f, -0.92387953251f};
    constexpr float im[10] = {0.f, -0.38268343236f, -0.70710678119f, -0.92387953251f, -1.f,
                              -0.92387953251f, -0.70710678119f, -0.38268343236f, 0.f, 0.38268343236f};
    return make_float2(re[k], INV ? -im[k] : im[k]);
}
template<bool INV>
__device__ __forceinline__ cplx w6k(int k){   // W6^k (conj if INV), k in {1,2}
    const float rr = (k == 1) ? 0.5f : -0.5f;
    const float ii = INV ? 0.86602540378f : -0.86602540378f;
    return make_float2(rr, ii);
}

template<bool INV>
__device__ __forceinline__ void r4(cplx& a0, cplx& a1, cplx& a2, cplx& a3){
    cplx t0 = caddc(a0, a2), t1 = csubc(a0, a2);
    cplx t2 = caddc(a1, a3), t3 = csubc(a1, a3);
    cplx it3 = INV ? make_float2(-t3.y, t3.x) : make_float2(t3.y, -t3.x);
    a0 = caddc(t0, t2); a1 = caddc(t1, it3);
    a2 = csubc(t0, t2); a3 = csubc(t1, it3);
}
template<bool INV>
__device__ __forceinline__ void r3(cplx& a0, cplx& a1, cplx& a2){
    cplx t1 = caddc(a1, a2), t2 = csubc(a1, a2);
    cplx m1 = make_float2(a0.x - 0.5f * t1.x, a0.y - 0.5f * t1.y);
    const float s3 = INV ? -0.8660254037844386f : 0.8660254037844386f;
    cplx b1 = make_float2(m1.x + s3 * t2.y, m1.y - s3 * t2.x);
    cplx b2 = make_float2(m1.x - s3 * t2.y, m1.y + s3 * t2.x);
    a0 = caddc(a0, t1); a1 = b1; a2 = b2;
}

// natural-order DFT-16 (two radix-4 Stockham stages in registers)
template<bool INV>
__device__ __forceinline__ void dft16(cplx x[16]){
    cplx y[16];
    #pragma unroll
    for (int j = 0; j < 4; ++j){
        cplx a0 = x[j], a1 = x[j+4], a2 = x[j+8], a3 = x[j+12];
        r4<INV>(a0, a1, a2, a3);
        y[4*j+0] = a0;
        y[4*j+1] = (j == 0) ? a1 : cmulc(a1, w16k<INV>(j));
        y[4*j+2] = (j == 0) ? a2 : cmulc(a2, w16k<INV>(2*j));
        y[4*j+3] = (j == 0) ? a3 : cmulc(a3, w16k<INV>(3*j));
    }
    #pragma unroll
    for (int q = 0; q < 4; ++q){
        cplx a0 = y[q], a1 = y[q+4], a2 = y[q+8], a3 = y[q+12];
        r4<INV>(a0, a1, a2, a3);
        x[q] = a0; x[q+4] = a1; x[q+8] = a2; x[q+12] = a3;
    }
}
// natural-order DFT-6 (radix-3 + radix-2 stages in registers)
template<bool INV>
__device__ __forceinline__ void dft6(cplx x[6]){
    cplx y[6];
    { cplx a0 = x[0], a1 = x[2], a2 = x[4]; r3<INV>(a0, a1, a2); y[0] = a0; y[1] = a1; y[2] = a2; }
    { cplx a0 = x[1], a1 = x[3], a2 = x[5]; r3<INV>(a0, a1, a2);
      y[3] = a0; y[4] = cmulc(a1, w6k<INV>(1)); y[5] = cmulc(a2, w6k<INV>(2)); }
    #pragma unroll
    for (int q = 0; q < 3; ++q){
        cplx s = caddc(y[q], y[q+3]), d = csubc(y[q], y[q+3]);
        x[q] = s; x[q+3] = d;
    }
}

// scatter 16 outputs with outer-twiddle power chain: dst[v*STR] = c[v] * w1^v
template<int STR>
__device__ __forceinline__ void scat16(cplx* dst, const cplx c[16], cplx w1){
    dst[0] = c[0];
    cplx tt = w1;
    #pragma unroll
    for (int v = 1; v < 16; ++v){
        dst[v * STR] = cmulc(c[v], tt);
        tt = cmulc(tt, w1);
    }
}

// ---------------------------------------------------------------------------
// K1: coil = csm*p; padded row FFT 96->288 via 3 sub-FFT96 with twiddles.
// FFT96 = radix-16 pass (registers, gathers from regs) + radix-6 pass
// (in-place, p=0, no outer twiddles) fused with the global store.
// ---------------------------------------------------------------------------
__global__ __launch_bounds__(512, 4)
void k_fwd_row(const cplx* __restrict__ pv, const cplx* __restrict__ csm,
               cplx* __restrict__ g, int cg0, int ncg, int ncga)
{
    __shared__ cplx A[NR * TILE];   // [s][t], stride TILE (all wave accesses t-contiguous)
    const int tid  = threadIdx.x;
    const int bid  = blockIdx.x;
    const int tile = bid % TILES;
    const int rem  = bid / TILES;
    const int gc   = rem % ncg;
    const int b    = rem / ncg;
    const int c    = cg0 + gc;
    const int colbase = tile * TILE;

    const cplx* pp = pv  + (size_t)b * NVOX;
    const cplx* cs = csm + ((size_t)b * C_ + c) * NVOX;
    cplx* gg = g + (size_t)(b * ncga + gc) * ((size_t)NP * NCOL);

    const bool act = tid < 288;
    const int t_ = tid % TILE;   // column in tile
    const int j_ = tid / TILE;   // 0..5 when active

    cplx xr[16];
    if (act){
        #pragma unroll
        for (int u = 0; u < 16; ++u){
            const int y  = j_ + 6 * u;
            const int gi = y * NCOL + colbase + t_;
            xr[u] = cmulc(pp[gi], cs[gi]);
        }
    }

    for (int a = 0; a < 3; ++a){
        if (a) __syncthreads();               // pass2 of prev a finished reading A
        if (act){
            cplx cv[16];
            // input twiddle tw288[a*(j+6u)] = base * step^u  (exact identity for a=0)
            const cplx bse = twf((float)(a * j_), R288);
            const cplx stp = twf((float)a, R48);
            cplx tt = bse;
            #pragma unroll
            for (int u = 0; u < 16; ++u){ cv[u] = cmulc(xr[u], tt); tt = cmulc(tt, stp); }
            dft16<false>(cv);
            scat16<TILE>(&A[(16 * j_) * TILE + t_], cv, twf((float)j_, R96));
        }
        __syncthreads();
        const cplx pref = twf((float)(32 * a), R96);   // e^{-2pi i a/3}
        #pragma unroll
        for (int it = 0; it < 2; ++it){
            const int bf = tid + it * 512;
            if (bf < 768){
                const int t2 = bf % TILE, j2 = bf / TILE;
                cplx c6[6];
                #pragma unroll
                for (int u = 0; u < 6; ++u) c6[u] = A[(j2 + 16 * u) * TILE + t2];
                dft6<false>(c6);
                #pragma unroll
                for (int u = 0; u < 6; ++u)
                    gg[(size_t)(3 * (j2 + 16 * u) + a) * NCOL + colbase + t2] = cmulc(c6[u], pref);
            }
        }
    }
}

// ---------------------------------------------------------------------------
// K2: per (b, coil, padded row): g <- conj(w) * IFFT2( mask/4608 * FFT2( w*g ) )
// 96x48 plane in LDS (stride 49). 8 passes total: each dim = radix16 + {3,6},
// with global load / mask / conj(w)+store folded into pass gathers/scatters.
// ---------------------------------------------------------------------------
__global__ __launch_bounds__(512, 4)
void k_plane(cplx* __restrict__ g, const cplx* __restrict__ wpsf,
             const float* __restrict__ mask, int ncg, int ncga)
{
    __shared__ cplx A[NC_ * LSTR];
    const int tid = threadIdx.x;
    const int bid = blockIdx.x;
    const int r   = bid % NP;
    const int rem = bid / NP;
    const int gc  = rem % ncg;
    const int b   = rem / ncg;

    cplx* gg = g + ((size_t)(b * ncga + gc) * NP + r) * NCOL;
    const cplx*  wp = wpsf + ((size_t)b * NP + r) * NCOL;
    const float* mk = mask + ((size_t)b * NP + r) * NCOL;

    // ---- fwd ns-FFT48 pass1 (radix-16) sourced from global, x w -------------
    if (tid < 288){
        const int nc = tid % 96, j = tid / 96;   // j<3
        cplx c[16];
        #pragma unroll
        for (int u = 0; u < 16; ++u){
            const int e = nc * NS + j + 3 * u;
            c[u] = cmulc(gg[e], wp[e]);
        }
        dft16<false>(c);
        scat16<1>(&A[nc * LSTR + 16 * j], c, twf(2.f * (float)j, R96));
    }
    __syncthreads();
    // ---- fwd ns pass2 (radix-3, p=0, in place) ------------------------------
    #pragma unroll
    for (int it = 0; it < 3; ++it){
        const int bf = tid + it * 512;           // 1536 = 3*512, exact
        const int nc = bf >> 4, j2 = bf & 15;
        cplx a0 = A[nc*LSTR + j2], a1 = A[nc*LSTR + j2 + 16], a2 = A[nc*LSTR + j2 + 32];
        r3<false>(a0, a1, a2);
        A[nc*LSTR + j2] = a0; A[nc*LSTR + j2 + 16] = a1; A[nc*LSTR + j2 + 32] = a2;
    }
    __syncthreads();
    // ---- fwd nc-FFT96 pass1 (radix-16): gather-all / barrier / scatter ------
    {
        cplx d[16];
        const int ns_ = tid % 48, j = tid / 48;  // j<6 when tid<288
        if (tid < 288){
            #pragma unroll
            for (int u = 0; u < 16; ++u) d[u] = A[(j + 6 * u) * LSTR + ns_];
        }
        __syncthreads();
        if (tid < 288){
            dft16<false>(d);
            scat16<LSTR>(&A[(16 * j) * LSTR + ns_], d, twf((float)j, R96));
        }
    }
    __syncthreads();
    // ---- fwd nc pass2 (radix-6, p=0, in place) + mask/4608 ------------------
    #pragma unroll
    for (int it = 0; it < 2; ++it){
        const int bf = tid + it * 512;
        if (bf < 768){
            const int ns_ = bf % 48, j2 = bf / 48;
            cplx c6[6];
            #pragma unroll
            for (int u = 0; u < 6; ++u) c6[u] = A[(j2 + 16 * u) * LSTR + ns_];
            dft6<false>(c6);
            #pragma unroll
            for (int u = 0; u < 6; ++u){
                const float m = mk[(j2 + 16 * u) * NS + ns_] * (1.f / 4608.f);
                c6[u].x *= m; c6[u].y *= m;
                A[(j2 + 16 * u) * LSTR + ns_] = c6[u];
            }
        }
    }
    __syncthreads();
    // ---- inv nc pass1 (radix-16, conj) --------------------------------------
    {
        cplx d[16];
        const int ns_ = tid % 48, j = tid / 48;
        if (tid < 288){
            #pragma unroll
            for (int u = 0; u < 16; ++u) d[u] = A[(j + 6 * u) * LSTR + ns_];
        }
        __syncthreads();
        if (tid < 288){
            dft16<true>(d);
            scat16<LSTR>(&A[(16 * j) * LSTR + ns_], d, twf(-(float)j, R96));
        }
    }
    __syncthreads();
    // ---- inv nc pass2 (radix-6, in place) -----------------------------------
    #pragma unroll
    for (int it = 0; it < 2; ++it){
        const int bf = tid + it * 512;
        if (bf < 768){
            const int ns_ = bf % 48, j2 = bf / 48;
            cplx c6[6];
            #pragma unroll
            for (int u = 0; u < 6; ++u) c6[u] = A[(j2 + 16 * u) * LSTR + ns_];
            dft6<true>(c6);
            #pragma unroll
            for (int u = 0; u < 6; ++u) A[(j2 + 16 * u) * LSTR + ns_] = c6[u];
        }
    }
    __syncthreads();
    // ---- inv ns pass1 (radix-16, conj) --------------------------------------
    {
        cplx e16[16];
        const int nc = tid % 96, j = tid / 96;
        if (tid < 288){
            #pragma unroll
            for (int u = 0; u < 16; ++u) e16[u] = A[nc * LSTR + j + 3 * u];
        }
        __syncthreads();
        if (tid < 288){
            dft16<true>(e16);
            scat16<1>(&A[nc * LSTR + 16 * j], e16, twf(-2.f * (float)j, R96));
        }
    }
    __syncthreads();
    // ---- inv ns pass2 (radix-3, in place) x conj(w), store global -----------
    #pragma unroll
    for (int it = 0; it < 3; ++it){
        const int bf = tid + it * 512;
        const int nc = bf >> 4, j2 = bf & 15;
        cplx a0 = A[nc*LSTR + j2], a1 = A[nc*LSTR + j2 + 16], a2 = A[nc*LSTR + j2 + 32];
        r3<true>(a0, a1, a2);
        const int e0 = nc * NS + j2;
        gg[e0]      = cmuljc(a0, wp[e0]);
        gg[e0 + 16] = cmuljc(a1, wp[e0 + 16]);
        gg[e0 + 32] = cmuljc(a2, wp[e0 + 32]);
    }
}

// ---------------------------------------------------------------------------
// K3: row IFFT 288->96 (crop): per a, radix-16 pass sourced from global,
// radix-6 pass accumulates conj-twiddled result into registers; epilogue
// does conj(csm)* and fp32 atomics into Ap.
// ---------------------------------------------------------------------------
__global__ __launch_bounds__(512, 4)
void k_inv_row(const cplx* __restrict__ g, const cplx* __restrict__ csm,
               float* __restrict__ Ap, int cg0, int ncg, int ncga)
{
    __shared__ cplx A[NR * TILE];
    const int tid  = threadIdx.x;
    const int bid  = blockIdx.x;
    const int tile = bid % TILES;
    const int rem  = bid / TILES;
    const int gc   = rem % ncg;
    const int b    = rem / ncg;
    const int c    = cg0 + gc;
    const int colbase = tile * TILE;

    const cplx* gg = g + (size_t)(b * ncga + gc) * ((size_t)NP * NCOL);

    const bool act = tid < 288;
    const int t_ = tid % TILE;
    const int j_ = tid / TILE;

    cplx acc[2][6];
    #pragma unroll
    for (int it = 0; it < 2; ++it)
        #pragma unroll
        for (int u = 0; u < 6; ++u) acc[it][u] = make_float2(0.f, 0.f);

    for (int a = 0; a < 3; ++a){
        if (a) __syncthreads();
        if (act){
            cplx cv[16];
            #pragma unroll
            for (int u = 0; u < 16; ++u)
                cv[u] = gg[(size_t)(3 * (j_ + 6 * u) + a) * NCOL + colbase + t_];
            dft16<true>(cv);
            scat16<TILE>(&A[(16 * j_) * TILE + t_], cv, twf(-(float)j_, R96));
        }
        __syncthreads();
        #pragma unroll
        for (int it = 0; it < 2; ++it){
            const int bf = tid + it * 512;
            if (bf < 768){
                const int t2 = bf % TILE, j2 = bf / TILE;
                cplx c6[6];
                #pragma unroll
                for (int u = 0; u < 6; ++u) c6[u] = A[(j2 + 16 * u) * TILE + t2];
                dft6<true>(c6);
                #pragma unroll
                for (int u = 0; u < 6; ++u){
                    const int y = j2 + 16 * u;
                    // conj(tw288[a*y]) * conj(e^{-2pi i a/3}) = e^{+2pi i a(y+96)/288}
                    const cplx f = twf(-(float)(a * (y + 96)), R288);
                    acc[it][u] = caddc(acc[it][u], cmulc(c6[u], f));
                }
            }
        }
    }

    const cplx* cs = csm + ((size_t)b * C_ + c) * NVOX;
    float* apb = Ap + (size_t)b * NVOX * 2;
    #pragma unroll
    for (int it = 0; it < 2; ++it){
        const int bf = tid + it * 512;
        if (bf < 768){
            const int t2 = bf % TILE, j2 = bf / TILE;
            #pragma unroll
            for (int u = 0; u < 6; ++u){
                const int y  = j2 + 16 * u;
                const int gi = y * NCOL + colbase + t2;
                cplx av = acc[it][u];
                av.x *= (1.f / 288.f); av.y *= (1.f / 288.f);
                const cplx v = cmuljc(av, cs[gi]);
                atomAddF(&apb[2 * gi],     v.x);
                atomAddF(&apb[2 * gi + 1], v.y);
            }
        }
    }
}

// ---------------------------------------------------------------------------
// CG helper kernels
// ---------------------------------------------------------------------------
__device__ inline float block_reduce_sum256(float v){
    #pragma unroll
    for (int o = 32; o >= 1; o >>= 1) v += __shfl_down(v, o, 64);
    __shared__ float sh[4];
    const int lane = threadIdx.x & 63, wv = threadIdx.x >> 6;
    if (lane == 0) sh[wv] = v;
    __syncthreads();
    float s = 0.f;
    if (threadIdx.x == 0) { s = sh[0] + sh[1] + sh[2] + sh[3]; }
    return s;
}

__global__ __launch_bounds__(256)
void k_rr0(const cplx* __restrict__ r, float* __restrict__ sc)
{
    const int i = blockIdx.x * 256 + threadIdx.x;
    const int b = i / NVOX;
    const cplx rv = r[i];
    const float s = block_reduce_sum256(rv.x * rv.x + rv.y * rv.y);
    if (threadIdx.x == 0) atomAddF(&sc[SC_RTR + b], s);
}

__global__ __launch_bounds__(256)
void k_lam_dot(cplx* __restrict__ Ap, const cplx* __restrict__ p,
               const float* __restrict__ lam1, float* __restrict__ sc)
{
    const int i = blockIdx.x * 256 + threadIdx.x;
    const int b = i / NVOX;
    const float lam = lam1[0];
    const cplx pv = p[i];
    cplx ap = Ap[i];
    ap.x += lam * pv.x; ap.y += lam * pv.y;
    Ap[i] = ap;
    const float s = block_reduce_sum256(pv.x * ap.x + pv.y * ap.y);
    if (threadIdx.x == 0) atomAddF(&sc[SC_PAP + b], s);
}

__global__ void k_alpha(float* sc)
{
    const int b = threadIdx.x;
    if (b < B_) {
        const float rtr = sc[SC_RTR + b];
        sc[SC_ACT + b]   = (rtr > 1e-5f) ? 1.f : 0.f;
        sc[SC_ALPHA + b] = rtr / sc[SC_PAP + b];
        sc[SC_RTR1 + b]  = 0.f;
    }
}

__global__ __launch_bounds__(256)
void k_update(cplx* __restrict__ x, cplx* __restrict__ r,
              const cplx* __restrict__ p, const cplx* __restrict__ Ap,
              float* __restrict__ sc)
{
    const int i = blockIdx.x * 256 + threadIdx.x;
    const int b = i / NVOX;
    float loc = 0.f;
    if (sc[SC_ACT + b] != 0.f) {
        const float al = sc[SC_ALPHA + b];
        cplx xv = x[i], rv = r[i];
        const cplx pv = p[i], av = Ap[i];
        xv.x += al * pv.x; xv.y += al * pv.y;
        rv.x -= al * av.x; rv.y -= al * av.y;
        x[i] = xv; r[i] = rv;
        loc = rv.x * rv.x + rv.y * rv.y;
    }
    const float s = block_reduce_sum256(loc);
    if (threadIdx.x == 0) atomAddF(&sc[SC_RTR1 + b], s);
}

__global__ void k_beta(float* sc)
{
    const int b = threadIdx.x;
    if (b < B_) {
        if (sc[SC_ACT + b] != 0.f) {
            sc[SC_BETA + b] = sc[SC_RTR1 + b] / sc[SC_RTR + b];
            sc[SC_RTR + b]  = sc[SC_RTR1 + b];
        } else {
            sc[SC_BETA + b] = 0.f;
        }
        sc[SC_PAP + b] = 0.f;   // pre-zero for next iteration
    }
}

__global__ __launch_bounds__(256)
void k_pupd(cplx* __restrict__ p, const cplx* __restrict__ r,
            const float* __restrict__ sc)
{
    const int i = blockIdx.x * 256 + threadIdx.x;
    const int b = i / NVOX;
    if (sc[SC_ACT + b] != 0.f) {
        const float be = sc[SC_BETA + b];
        const cplx pv = p[i], rv = r[i];
        p[i] = make_float2(rv.x + be * pv.x, rv.y + be * pv.y);
    }
}

// ---------------------------------------------------------------------------
extern "C" void kernel_launch(void* const* d_in, const int* in_sizes, int n_in,
                              void* d_out, int out_size, void* d_ws, size_t ws_size,
                              hipStream_t stream)
{
    const cplx*  rhs  = (const cplx*)d_in[0];
    const cplx*  csm  = (const cplx*)d_in[1];
    const float* mask = (const float*)d_in[2];
    const cplx*  wpsf = (const cplx*)d_in[3];
    const float* lam1 = (const float*)d_in[4];

    const size_t vb = (size_t)B_ * NVOX * sizeof(cplx);   // 7,077,888 B
    char* ws = (char*)d_ws;
    float* sc = (float*)ws;
    cplx* Ap = (cplx*)(ws + 256);
    cplx* r  = (cplx*)(ws + 256 + vb);
    cplx* p  = (cplx*)(ws + 256 + 2 * vb);
    cplx* g  = (cplx*)(ws + 256 + 3 * vb);
    cplx* x  = (cplx*)d_out;

    const size_t fixed   = 256 + 3 * vb;
    const size_t percoil = (size_t)B_ * NP * NCOL * sizeof(cplx);  // 21,233,664 B
    int ncga = 1;
    if (ws_size > fixed) {
        size_t fit = (ws_size - fixed) / percoil;
        ncga = (fit < 1) ? 1 : (fit > (size_t)C_ ? C_ : (int)fit);
    }

    hipMemsetAsync(d_out, 0, vb, stream);       // x0 = 0
    hipMemsetAsync(sc, 0, 256, stream);
    hipMemcpyAsync(r, rhs, vb, hipMemcpyDeviceToDevice, stream);
    hipMemcpyAsync(p, rhs, vb, hipMemcpyDeviceToDevice, stream);
    k_rr0<<<(B_ * NVOX) / 256, 256, 0, stream>>>(r, sc);

    for (int it = 0; it < 10; ++it) {
        hipMemsetAsync(Ap, 0, vb, stream);
        for (int cg0 = 0; cg0 < C_; cg0 += ncga) {
            const int ncg = (C_ - cg0 < ncga) ? (C_ - cg0) : ncga;
            k_fwd_row<<<TILES * ncg * B_, 512, 0, stream>>>(p, csm, g, cg0, ncg, ncga);
            k_plane  <<<NP    * ncg * B_, 512, 0, stream>>>(g, wpsf, mask, ncg, ncga);
            k_inv_row<<<TILES * ncg * B_, 512, 0, stream>>>(g, csm, (float*)Ap, cg0, ncg, ncga);
        }
        k_lam_dot<<<(B_ * NVOX) / 256, 256, 0, stream>>>(Ap, p, lam1, sc);
        k_alpha  <<<1, 64, 0, stream>>>(sc);
        k_update <<<(B_ * NVOX) / 256, 256, 0, stream>>>(x, r, p, Ap, sc);
        k_beta   <<<1, 64, 0, stream>>>(sc);
        k_pupd   <<<(B_ * NVOX) / 256, 256, 0, stream>>>(p, r, sc);
    }
}

// Round 5
// 8266.135 us; speedup vs baseline: 1.1501x; 1.1501x over previous
//
#include <hip/hip_runtime.h>

typedef float2 cplx;

constexpr int B_   = 2;
constexpr int C_   = 12;
constexpr int NR   = 96;
constexpr int NC_  = 96;
constexpr int NS   = 48;
constexpr int NP   = 288;
constexpr int NCOL = NC_ * NS;      // 4608
constexpr int NVOX = NR * NCOL;     // 442368
constexpr int TILE = 48;
constexpr int TILES = NCOL / TILE;  // 96
constexpr int LSTR = 49;            // padded y/nc stride in LDS
constexpr int CPB  = 3;             // coils per k_inv block
constexpr int NGRP = 4;             // 12 / CPB
constexpr float PI2 = 6.28318530717958647692f;
constexpr float R96 = 1.f/96.f, R48 = 1.f/48.f, R288 = 1.f/288.f;

// scalar slots: rtr ping-pong at 0,1 / 2,3 ; pAp at 4,5
__device__ inline cplx cmulc(cplx a, cplx b){ return make_float2(a.x*b.x - a.y*b.y, a.x*b.y + a.y*b.x); }
__device__ inline cplx cmuljc(cplx a, cplx b){ return make_float2(a.x*b.x + a.y*b.y, a.y*b.x - a.x*b.y); }
__device__ inline cplx caddc(cplx a, cplx b){ return make_float2(a.x+b.x, a.y+b.y); }
__device__ inline cplx csubc(cplx a, cplx b){ return make_float2(a.x-b.x, a.y-b.y); }

__device__ inline void atomAddF(float* p, float v){
    __hip_atomic_fetch_add(p, v, __ATOMIC_RELAXED, __HIP_MEMORY_SCOPE_AGENT);
}

__device__ __forceinline__ cplx twf(float k, float rN){
    float s, c; __sincosf(-PI2 * k * rN, &s, &c);
    return make_float2(c, s);
}

// ---------------- register DFT cores ----------------
template<bool INV>
__device__ __forceinline__ cplx w16k(int k){
    constexpr float re[10] = {1.f, 0.92387953251f, 0.70710678119f, 0.38268343236f, 0.f,
                              -0.38268343236f, -0.70710678119f, -0.92387953251f, -1.f, -0.92387953251f};
    constexpr float im[10] = {0.f, -0.38268343236f, -0.70710678119f, -0.92387953251f, -1.f,
                              -0.92387953251f, -0.70710678119f, -0.38268343236f, 0.f, 0.38268343236f};
    return make_float2(re[k], INV ? -im[k] : im[k]);
}
template<bool INV>
__device__ __forceinline__ cplx w6k(int k){
    const float rr = (k == 1) ? 0.5f : -0.5f;
    const float ii = INV ? 0.86602540378f : -0.86602540378f;
    return make_float2(rr, ii);
}
template<bool INV>
__device__ __forceinline__ void r4(cplx& a0, cplx& a1, cplx& a2, cplx& a3){
    cplx t0 = caddc(a0, a2), t1 = csubc(a0, a2);
    cplx t2 = caddc(a1, a3), t3 = csubc(a1, a3);
    cplx it3 = INV ? make_float2(-t3.y, t3.x) : make_float2(t3.y, -t3.x);
    a0 = caddc(t0, t2); a1 = caddc(t1, it3);
    a2 = csubc(t0, t2); a3 = csubc(t1, it3);
}
template<bool INV>
__device__ __forceinline__ void r3(cplx& a0, cplx& a1, cplx& a2){
    cplx t1 = caddc(a1, a2), t2 = csubc(a1, a2);
    cplx m1 = make_float2(a0.x - 0.5f * t1.x, a0.y - 0.5f * t1.y);
    const float s3 = INV ? -0.8660254037844386f : 0.8660254037844386f;
    cplx b1 = make_float2(m1.x + s3 * t2.y, m1.y - s3 * t2.x);
    cplx b2 = make_float2(m1.x - s3 * t2.y, m1.y + s3 * t2.x);
    a0 = caddc(a0, t1); a1 = b1; a2 = b2;
}
template<bool INV>
__device__ __forceinline__ void dft16(cplx x[16]){
    cplx y[16];
    #pragma unroll
    for (int j = 0; j < 4; ++j){
        cplx a0 = x[j], a1 = x[j+4], a2 = x[j+8], a3 = x[j+12];
        r4<INV>(a0, a1, a2, a3);
        y[4*j+0] = a0;
        y[4*j+1] = (j == 0) ? a1 : cmulc(a1, w16k<INV>(j));
        y[4*j+2] = (j == 0) ? a2 : cmulc(a2, w16k<INV>(2*j));
        y[4*j+3] = (j == 0) ? a3 : cmulc(a3, w16k<INV>(3*j));
    }
    #pragma unroll
    for (int q = 0; q < 4; ++q){
        cplx a0 = y[q], a1 = y[q+4], a2 = y[q+8], a3 = y[q+12];
        r4<INV>(a0, a1, a2, a3);
        x[q] = a0; x[q+4] = a1; x[q+8] = a2; x[q+12] = a3;
    }
}
template<bool INV>
__device__ __forceinline__ void dft6(cplx x[6]){
    cplx y[6];
    { cplx a0 = x[0], a1 = x[2], a2 = x[4]; r3<INV>(a0, a1, a2); y[0] = a0; y[1] = a1; y[2] = a2; }
    { cplx a0 = x[1], a1 = x[3], a2 = x[5]; r3<INV>(a0, a1, a2);
      y[3] = a0; y[4] = cmulc(a1, w6k<INV>(1)); y[5] = cmulc(a2, w6k<INV>(2)); }
    #pragma unroll
    for (int q = 0; q < 3; ++q){
        cplx s = caddc(y[q], y[q+3]), d = csubc(y[q], y[q+3]);
        x[q] = s; x[q+3] = d;
    }
}

// ---------------------------------------------------------------------------
// K1: coil = csm*p, padded row FFT 96->288: G[3(6t+r)+a] = W3^a * X_a[6t+r],
// X_a = FFT96(x * W288^{a y}) via DIF 6x16 (pass1 from global, in-place LDS).
// ---------------------------------------------------------------------------
__global__ __launch_bounds__(512, 4)
void k_fwd(const cplx* __restrict__ pv, const cplx* __restrict__ csm,
           cplx* __restrict__ g, int cg0, int ncg, int ncga)
{
    __shared__ cplx A[NR * LSTR];
    const int tid = threadIdx.x, bid = blockIdx.x;
    const int tile = bid % TILES;
    const int rem = bid / TILES;
    const int gc = rem % ncg, b = rem / ncg, c = cg0 + gc;
    const int colbase = tile * TILE;
    const cplx* pp = pv  + (size_t)b * NVOX;
    const cplx* cs = csm + ((size_t)b * C_ + c) * NVOX;
    cplx* gg = g + (size_t)(b * ncga + gc) * ((size_t)NP * NCOL);

    for (int a = 0; a < 3; ++a){
        if (a) __syncthreads();
        // pass1 (radix-6, 768 items): gather global, input twiddle, dft6, xW96^{mr}
        #pragma unroll
        for (int it = 0; it < 2; ++it){
            const int id = tid + it * 512;
            if (id < 768){
                const int m = id / TILE, col = id - m * TILE;
                cplx xv[6];
                #pragma unroll
                for (int v = 0; v < 6; ++v){
                    const int gi = (m + 16*v) * NCOL + colbase + col;
                    xv[v] = cmulc(pp[gi], cs[gi]);
                }
                if (a){
                    cplx t = twf((float)(a*m), R288);
                    const cplx stp = twf((float)(16*a), R288);
                    #pragma unroll
                    for (int v = 0; v < 6; ++v){ xv[v] = cmulc(xv[v], t); t = cmulc(t, stp); }
                }
                dft6<false>(xv);
                cplx* dst = &A[m * LSTR + col];
                dst[0] = xv[0];
                const cplx w1 = twf((float)m, R96);
                cplx t = w1;
                #pragma unroll
                for (int r = 1; r < 6; ++r){ dst[16*r*LSTR] = cmulc(xv[r], t); t = cmulc(t, w1); }
            }
        }
        __syncthreads();
        // pass2 (radix-16, 288 items) fused with global store
        if (tid < 288){
            const int r = tid / TILE, col = tid - r * TILE;
            cplx d[16];
            #pragma unroll
            for (int m = 0; m < 16; ++m) d[m] = A[(m + 16*r) * LSTR + col];
            dft16<false>(d);
            const cplx pref = twf((float)(32*a), R96);   // e^{-2pi i a/3}
            #pragma unroll
            for (int t = 0; t < 16; ++t)
                gg[(size_t)(18*t + 3*r + a) * NCOL + colbase + col] = cmulc(d[t], pref);
        }
    }
}

// ---------------------------------------------------------------------------
// K2: per padded row: g <- conj(w) * IFFT2( pm * FFT2( w*g ) ), DIF->DIT,
// mask permuted (pm3), all passes in-place, turnaround fused in registers.
// ---------------------------------------------------------------------------
__global__ __launch_bounds__(512, 4)
void k_plane(cplx* __restrict__ g, const cplx* __restrict__ wpsf,
             const float* __restrict__ pm3, int ncg, int ncga)
{
    __shared__ cplx A[NC_ * LSTR];
    const int tid = threadIdx.x, bid = blockIdx.x;
    const int rp = bid % NP;
    const int rem = bid / NP;
    const int gc = rem % ncg, b = rem / ncg;
    cplx* gg = g + ((size_t)(b * ncga + gc) * NP + rp) * NCOL;
    const cplx*  wp  = wpsf + ((size_t)b * NP + rp) * NCOL;
    const float* pmv = pm3  + ((size_t)b * NP + rp) * NCOL;

    // ph1: ns DIF p1 (radix-3) from global, x w
    #pragma unroll
    for (int it = 0; it < 3; ++it){
        const int id = tid + it * 512;
        const int m = id & 15, nc = id >> 4;
        cplx xv[3];
        #pragma unroll
        for (int v = 0; v < 3; ++v){
            const int e = nc * NS + m + 16*v;
            xv[v] = cmulc(gg[e], wp[e]);
        }
        r3<false>(xv[0], xv[1], xv[2]);
        cplx* dst = &A[nc * LSTR + m];
        const cplx w1 = twf((float)m, R48);
        dst[0]  = xv[0];
        dst[16] = cmulc(xv[1], w1);
        dst[32] = cmulc(xv[2], cmulc(w1, w1));
    }
    __syncthreads();
    // ph2: ns DIF p2 (radix-16, contiguous blocks, in place)
    if (tid < 288){
        const int rho = tid / 96, nc = tid - rho * 96;
        cplx* pA = &A[nc * LSTR + 16 * rho];
        cplx d[16];
        #pragma unroll
        for (int m = 0; m < 16; ++m) d[m] = pA[m];
        dft16<false>(d);
        #pragma unroll
        for (int t = 0; t < 16; ++t) pA[t] = d[t];
    }
    __syncthreads();
    // ph3: nc DIF p1 (radix-6, in place)
    #pragma unroll
    for (int it = 0; it < 2; ++it){
        const int id = tid + it * 512;
        if (id < 768){
            const int m = id / NS, ns = id - m * NS;
            cplx xv[6];
            #pragma unroll
            for (int v = 0; v < 6; ++v) xv[v] = A[(m + 16*v) * LSTR + ns];
            dft6<false>(xv);
            const cplx w1 = twf((float)m, R96);
            A[m * LSTR + ns] = xv[0];
            cplx t = w1;
            #pragma unroll
            for (int r = 1; r < 6; ++r){ A[(m + 16*r) * LSTR + ns] = cmulc(xv[r], t); t = cmulc(t, w1); }
        }
    }
    __syncthreads();
    // ph4: nc DIF p2 + permuted mask + nc DIT p2 — fully in registers
    if (tid < 288){
        const int r = tid / NS, ns = tid - r * NS;
        cplx d[16];
        #pragma unroll
        for (int m = 0; m < 16; ++m) d[m] = A[(m + 16*r) * LSTR + ns];
        dft16<false>(d);
        #pragma unroll
        for (int t = 0; t < 16; ++t){
            const float mval = pmv[(6*t + r) * NS + ns];
            d[t].x *= mval; d[t].y *= mval;
        }
        dft16<true>(d);
        #pragma unroll
        for (int m = 0; m < 16; ++m) A[(m + 16*r) * LSTR + ns] = d[m];
    }
    __syncthreads();
    // ph5: nc DIT p1 (undo radix-6, in place)
    #pragma unroll
    for (int it = 0; it < 2; ++it){
        const int id = tid + it * 512;
        if (id < 768){
            const int m = id / NS, ns = id - m * NS;
            cplx xv[6];
            const cplx w1 = twf(-(float)m, R96);
            cplx t = make_float2(1.f, 0.f);
            #pragma unroll
            for (int r = 0; r < 6; ++r){ xv[r] = cmulc(A[(m + 16*r) * LSTR + ns], t); t = cmulc(t, w1); }
            dft6<true>(xv);
            #pragma unroll
            for (int v = 0; v < 6; ++v) A[(m + 16*v) * LSTR + ns] = xv[v];
        }
    }
    __syncthreads();
    // ph6: ns DIT p2 (idft16 contiguous, in place)
    if (tid < 288){
        const int rho = tid / 96, nc = tid - rho * 96;
        cplx* pA = &A[nc * LSTR + 16 * rho];
        cplx d[16];
        #pragma unroll
        for (int t = 0; t < 16; ++t) d[t] = pA[t];
        dft16<true>(d);
        #pragma unroll
        for (int m = 0; m < 16; ++m) pA[m] = d[m];
    }
    __syncthreads();
    // ph7: ns DIT p1 (undo radix-3) x conj(w), store global
    #pragma unroll
    for (int it = 0; it < 3; ++it){
        const int id = tid + it * 512;
        const int m = id & 15, nc = id >> 4;
        const cplx w1 = twf(-(float)m, R48);
        cplx xv[3];
        xv[0] = A[nc * LSTR + m];
        xv[1] = cmulc(A[nc * LSTR + m + 16], w1);
        xv[2] = cmulc(A[nc * LSTR + m + 32], cmulc(w1, w1));
        r3<true>(xv[0], xv[1], xv[2]);
        #pragma unroll
        for (int v = 0; v < 3; ++v){
            const int e = nc * NS + m + 16*v;
            gg[e] = cmuljc(xv[v], wp[e]);
        }
    }
}

// ---------------------------------------------------------------------------
// K3: row IFFT 288->96 (crop) via DIT 16x6 per a-slice, 3 coils per block,
// register accumulation, per-group Ap slice (plain RMW stores, no atomics).
// ---------------------------------------------------------------------------
__global__ __launch_bounds__(512, 3)
void k_inv(const cplx* __restrict__ g, const cplx* __restrict__ csm,
           cplx* __restrict__ ap4, int cg0, int ncg, int ng, int ncga)
{
    __shared__ cplx A[NR * LSTR];
    const int tid = threadIdx.x, bid = blockIdx.x;
    const int tile = bid % TILES;
    const int rem = bid / TILES;
    const int gl = rem % ng, b = rem / ng;
    const int cbase = cg0 + gl * CPB;
    const int cnum = (ncg - gl * CPB) < CPB ? (ncg - gl * CPB) : CPB;
    const int grp = cbase / CPB;
    const int colbase = tile * TILE;
    cplx* apg = ap4 + ((size_t)grp * B_ + b) * NVOX;

    cplx acc[2][6];
    bool first = true;
    for (int ci = 0; ci < cnum; ++ci){
        const int c = cbase + ci;
        const cplx* gc_ = g + (size_t)(b * ncga + (c - cg0)) * ((size_t)NP * NCOL);
        const cplx* cs  = csm + ((size_t)b * C_ + c) * NVOX;
        #pragma unroll
        for (int it = 0; it < 2; ++it)
            #pragma unroll
            for (int j = 0; j < 6; ++j) acc[it][j] = make_float2(0.f, 0.f);

        for (int a = 0; a < 3; ++a){
            if (!first) __syncthreads();
            first = false;
            // DIT p1: idft16 over decimated global gathers -> LDS
            if (tid < 288){
                const int c6 = tid / TILE, col = tid - c6 * TILE;
                cplx d[16];
                #pragma unroll
                for (int u = 0; u < 16; ++u)
                    d[u] = gc_[(size_t)(3*(c6 + 6*u) + a) * NCOL + colbase + col];
                dft16<true>(d);
                #pragma unroll
                for (int q = 0; q < 16; ++q) A[(c6 + 6*q) * LSTR + col] = d[q];
            }
            __syncthreads();
            // DIT p2: x W96^{-cq}, idft6, fold f(a,y)/288, accumulate
            #pragma unroll
            for (int it = 0; it < 2; ++it){
                const int id = tid + it * 512;
                if (id < 768){
                    const int q = id / TILE, col = id - q * TILE;
                    cplx xv[6];
                    const cplx w1 = twf(-(float)q, R96);
                    cplx t = make_float2(1.f, 0.f);
                    #pragma unroll
                    for (int cc = 0; cc < 6; ++cc){ xv[cc] = cmulc(A[(cc + 6*q) * LSTR + col], t); t = cmulc(t, w1); }
                    dft6<true>(xv);
                    cplx f = twf(-(float)(a * (q + 96)), R288);
                    f.x *= (1.f/288.f); f.y *= (1.f/288.f);
                    const cplx fs = twf(-(float)(16 * a), R288);
                    #pragma unroll
                    for (int j = 0; j < 6; ++j){
                        acc[it][j] = caddc(acc[it][j], cmulc(xv[j], f));
                        f = cmulc(f, fs);
                    }
                }
            }
        }
        // epilogue: x conj(csm), merge into group slice
        #pragma unroll
        for (int it = 0; it < 2; ++it){
            const int id = tid + it * 512;
            if (id < 768){
                const int q = id / TILE, col = id - q * TILE;
                #pragma unroll
                for (int j = 0; j < 6; ++j){
                    const int y = q + 16*j;
                    const int gi = y * NCOL + colbase + col;
                    const cplx v = cmuljc(acc[it][j], cs[gi]);
                    if (ci == 0) apg[gi] = v;
                    else { cplx o = apg[gi]; apg[gi] = caddc(o, v); }
                }
            }
        }
    }
}

// ---------------------------------------------------------------------------
// permuted mask builder (once per solve): pm3[b][rp][k_nc][p_ns]
// ---------------------------------------------------------------------------
__global__ __launch_bounds__(512)
void k_pmb(const float* __restrict__ mask, float* __restrict__ pm3)
{
    const int bid = blockIdx.x;            // b*NP + rp
    const float* mk = mask + (size_t)bid * NCOL;
    float* out = pm3 + (size_t)bid * NCOL;
    for (int e = threadIdx.x; e < NCOL; e += 512){
        const int knc = e / NS, pns = e - knc * NS;
        const int kns = 3 * (pns & 15) + (pns >> 4);
        out[e] = mk[knc * NS + kns] * (1.f / 4608.f);
    }
}

// ---------------------------------------------------------------------------
// CG kernels (3 per iteration; alpha/beta recomputed per block from slots)
// ---------------------------------------------------------------------------
__device__ inline float block_reduce_sum256(float v){
    #pragma unroll
    for (int o = 32; o >= 1; o >>= 1) v += __shfl_down(v, o, 64);
    __shared__ float sh[4];
    const int lane = threadIdx.x & 63, wv = threadIdx.x >> 6;
    if (lane == 0) sh[wv] = v;
    __syncthreads();
    float s = 0.f;
    if (threadIdx.x == 0) { s = sh[0] + sh[1] + sh[2] + sh[3]; }
    return s;
}

__global__ __launch_bounds__(256)
void k_rr0(const cplx* __restrict__ r, float* __restrict__ sc)
{
    const int i = blockIdx.x * 256 + threadIdx.x;
    const int b = i / NVOX;
    const cplx rv = r[i];
    const float s = block_reduce_sum256(rv.x*rv.x + rv.y*rv.y);
    if (threadIdx.x == 0) atomAddF(&sc[0 + b], s);
}

__global__ __launch_bounds__(256)
void k_dot(const cplx* __restrict__ p, const cplx* __restrict__ ap4,
           const float* __restrict__ lam1, float* __restrict__ sc, int rn)
{
    const int i = blockIdx.x * 256 + threadIdx.x;
    const int b = i / NVOX;
    const float lam = lam1[0];
    const cplx pv = p[i];
    cplx ap = make_float2(lam * pv.x, lam * pv.y);
    #pragma unroll
    for (int gp = 0; gp < NGRP; ++gp){
        const cplx t = ap4[(size_t)gp * B_ * NVOX + i];
        ap.x += t.x; ap.y += t.y;
    }
    const float s = block_reduce_sum256(pv.x*ap.x + pv.y*ap.y);
    if (threadIdx.x == 0) atomAddF(&sc[4 + b], s);
    if (blockIdx.x == 0 && threadIdx.x < 2) sc[rn + threadIdx.x] = 0.f;
}

__global__ __launch_bounds__(256)
void k_update(cplx* __restrict__ x, cplx* __restrict__ r,
              const cplx* __restrict__ p, const cplx* __restrict__ ap4,
              const float* __restrict__ lam1, float* __restrict__ sc, int rc, int rn)
{
    const int i = blockIdx.x * 256 + threadIdx.x;
    const int b = i / NVOX;
    const float rtr = sc[rc + b];
    const bool act = rtr > 1e-5f;
    const float alpha = rtr / sc[4 + b];
    const float lam = lam1[0];
    const cplx pv = p[i];
    cplx ap = make_float2(lam * pv.x, lam * pv.y);
    #pragma unroll
    for (int gp = 0; gp < NGRP; ++gp){
        const cplx t = ap4[(size_t)gp * B_ * NVOX + i];
        ap.x += t.x; ap.y += t.y;
    }
    cplx rv = r[i];
    if (act){
        cplx xv = x[i];
        xv.x += alpha * pv.x; xv.y += alpha * pv.y;
        x[i] = xv;
        rv.x -= alpha * ap.x; rv.y -= alpha * ap.y;
        r[i] = rv;
    }
    const float s = block_reduce_sum256(rv.x*rv.x + rv.y*rv.y);
    if (threadIdx.x == 0) atomAddF(&sc[rn + b], s);
}

__global__ __launch_bounds__(256)
void k_pupd(cplx* __restrict__ p, const cplx* __restrict__ r,
            float* __restrict__ sc, int rc, int rn)
{
    const int i = blockIdx.x * 256 + threadIdx.x;
    const int b = i / NVOX;
    const float rtr = sc[rc + b];
    if (rtr > 1e-5f){
        const float be = sc[rn + b] / rtr;
        const cplx pv = p[i], rv = r[i];
        p[i] = make_float2(rv.x + be * pv.x, rv.y + be * pv.y);
    }
    if (blockIdx.x == 0 && threadIdx.x < 2) sc[4 + threadIdx.x] = 0.f;
}

// ---------------------------------------------------------------------------
extern "C" void kernel_launch(void* const* d_in, const int* in_sizes, int n_in,
                              void* d_out, int out_size, void* d_ws, size_t ws_size,
                              hipStream_t stream)
{
    const cplx*  rhs  = (const cplx*)d_in[0];
    const cplx*  csm  = (const cplx*)d_in[1];
    const float* mask = (const float*)d_in[2];
    const cplx*  wpsf = (const cplx*)d_in[3];
    const float* lam1 = (const float*)d_in[4];

    const size_t vb = (size_t)B_ * NVOX * sizeof(cplx);           // 7,077,888 B
    const size_t pmb = (size_t)B_ * NP * NCOL * sizeof(float);    // 10.6 MB
    const size_t percoil = (size_t)B_ * NP * NCOL * sizeof(cplx); // 21.2 MB

    char* ws = (char*)d_ws;
    float* sc = (float*)ws;
    size_t off = 256;
    cplx* r   = (cplx*)(ws + off); off += vb;
    cplx* p   = (cplx*)(ws + off); off += vb;
    float* pm3 = (float*)(ws + off); off += pmb;
    cplx* ap4 = (cplx*)(ws + off); off += (size_t)NGRP * vb;
    cplx* g   = (cplx*)(ws + off);
    cplx* x   = (cplx*)d_out;

    int ncga = 3;
    if (ws_size > off){
        size_t fit = (ws_size - off) / percoil;
        ncga = fit > (size_t)C_ ? C_ : (int)fit;
        ncga -= ncga % CPB;
        if (ncga < CPB) ncga = CPB;
    }

    hipMemsetAsync(d_out, 0, vb, stream);
    hipMemsetAsync(sc, 0, 256, stream);
    hipMemcpyAsync(r, rhs, vb, hipMemcpyDeviceToDevice, stream);
    hipMemcpyAsync(p, rhs, vb, hipMemcpyDeviceToDevice, stream);
    k_pmb<<<B_ * NP, 512, 0, stream>>>(mask, pm3);
    k_rr0<<<(B_ * NVOX) / 256, 256, 0, stream>>>(r, sc);

    for (int it = 0; it < 10; ++it){
        for (int cg0 = 0; cg0 < C_; cg0 += ncga){
            const int ncg = (C_ - cg0 < ncga) ? (C_ - cg0) : ncga;
            const int ng = (ncg + CPB - 1) / CPB;
            k_fwd  <<<TILES * ncg * B_, 512, 0, stream>>>(p, csm, g, cg0, ncg, ncga);
            k_plane<<<NP    * ncg * B_, 512, 0, stream>>>(g, wpsf, pm3, ncg, ncga);
            k_inv  <<<TILES * ng  * B_, 512, 0, stream>>>(g, csm, ap4, cg0, ncg, ng, ncga);
        }
        const int rc = (it & 1) ? 2 : 0, rn = 2 - rc;
        k_dot   <<<(B_ * NVOX) / 256, 256, 0, stream>>>(p, ap4, lam1, sc, rn);
        k_update<<<(B_ * NVOX) / 256, 256, 0, stream>>>(x, r, p, ap4, lam1, sc, rc, rn);
        k_pupd  <<<(B_ * NVOX) / 256, 256, 0, stream>>>(p, r, sc, rc, rn);
    }
}

// Round 6
// 6495.029 us; speedup vs baseline: 1.4637x; 1.2727x over previous
//
#include <hip/hip_runtime.h>
#include <hip/hip_fp16.h>

typedef float2 cplx;
typedef __half2 gpak;   // packed complex in fp16 (re, im)

constexpr int B_   = 2;
constexpr int C_   = 12;
constexpr int NR   = 96;
constexpr int NC_  = 96;
constexpr int NS   = 48;
constexpr int NP   = 288;
constexpr int NCOL = NC_ * NS;      // 4608
constexpr int NVOX = NR * NCOL;     // 442368
constexpr int TILE = 48;
constexpr int TILES = NCOL / TILE;  // 96
constexpr int LSTR = 49;            // padded y/nc stride in LDS
constexpr int CPB  = 3;             // coils per k_inv block
constexpr float PI2 = 6.28318530717958647692f;
constexpr float R96 = 1.f/96.f, R48 = 1.f/48.f, R288 = 1.f/288.f;

// scalar slots: rtr ping-pong at 0,1 / 2,3 ; pAp at 4,5
__device__ inline cplx cmulc(cplx a, cplx b){ return make_float2(a.x*b.x - a.y*b.y, a.x*b.y + a.y*b.x); }
__device__ inline cplx cmuljc(cplx a, cplx b){ return make_float2(a.x*b.x + a.y*b.y, a.y*b.x - a.x*b.y); }
__device__ inline cplx caddc(cplx a, cplx b){ return make_float2(a.x+b.x, a.y+b.y); }
__device__ inline cplx csubc(cplx a, cplx b){ return make_float2(a.x-b.x, a.y-b.y); }

__device__ __forceinline__ gpak pack_g(cplx v){ return __float22half2_rn(v); }
__device__ __forceinline__ cplx unpack_g(gpak h){ return __half22float2(h); }

__device__ inline void atomAddF(float* p, float v){
    __hip_atomic_fetch_add(p, v, __ATOMIC_RELAXED, __HIP_MEMORY_SCOPE_AGENT);
}

__device__ __forceinline__ cplx twf(float k, float rN){
    float s, c; __sincosf(-PI2 * k * rN, &s, &c);
    return make_float2(c, s);
}

// ---------------- register DFT cores ----------------
template<bool INV>
__device__ __forceinline__ cplx w16k(int k){
    constexpr float re[10] = {1.f, 0.92387953251f, 0.70710678119f, 0.38268343236f, 0.f,
                              -0.38268343236f, -0.70710678119f, -0.92387953251f, -1.f, -0.92387953251f};
    constexpr float im[10] = {0.f, -0.38268343236f, -0.70710678119f, -0.92387953251f, -1.f,
                              -0.92387953251f, -0.70710678119f, -0.38268343236f, 0.f, 0.38268343236f};
    return make_float2(re[k], INV ? -im[k] : im[k]);
}
template<bool INV>
__device__ __forceinline__ cplx w6k(int k){
    const float rr = (k == 1) ? 0.5f : -0.5f;
    const float ii = INV ? 0.86602540378f : -0.86602540378f;
    return make_float2(rr, ii);
}
template<bool INV>
__device__ __forceinline__ void r4(cplx& a0, cplx& a1, cplx& a2, cplx& a3){
    cplx t0 = caddc(a0, a2), t1 = csubc(a0, a2);
    cplx t2 = caddc(a1, a3), t3 = csubc(a1, a3);
    cplx it3 = INV ? make_float2(-t3.y, t3.x) : make_float2(t3.y, -t3.x);
    a0 = caddc(t0, t2); a1 = caddc(t1, it3);
    a2 = csubc(t0, t2); a3 = csubc(t1, it3);
}
template<bool INV>
__device__ __forceinline__ void r3(cplx& a0, cplx& a1, cplx& a2){
    cplx t1 = caddc(a1, a2), t2 = csubc(a1, a2);
    cplx m1 = make_float2(a0.x - 0.5f * t1.x, a0.y - 0.5f * t1.y);
    const float s3 = INV ? -0.8660254037844386f : 0.8660254037844386f;
    cplx b1 = make_float2(m1.x + s3 * t2.y, m1.y - s3 * t2.x);
    cplx b2 = make_float2(m1.x - s3 * t2.y, m1.y + s3 * t2.x);
    a0 = caddc(a0, t1); a1 = b1; a2 = b2;
}
template<bool INV>
__device__ __forceinline__ void dft16(cplx x[16]){
    cplx y[16];
    #pragma unroll
    for (int j = 0; j < 4; ++j){
        cplx a0 = x[j], a1 = x[j+4], a2 = x[j+8], a3 = x[j+12];
        r4<INV>(a0, a1, a2, a3);
        y[4*j+0] = a0;
        y[4*j+1] = (j == 0) ? a1 : cmulc(a1, w16k<INV>(j));
        y[4*j+2] = (j == 0) ? a2 : cmulc(a2, w16k<INV>(2*j));
        y[4*j+3] = (j == 0) ? a3 : cmulc(a3, w16k<INV>(3*j));
    }
    #pragma unroll
    for (int q = 0; q < 4; ++q){
        cplx a0 = y[q], a1 = y[q+4], a2 = y[q+8], a3 = y[q+12];
        r4<INV>(a0, a1, a2, a3);
        x[q] = a0; x[q+4] = a1; x[q+8] = a2; x[q+12] = a3;
    }
}
template<bool INV>
__device__ __forceinline__ void dft6(cplx x[6]){
    cplx y[6];
    { cplx a0 = x[0], a1 = x[2], a2 = x[4]; r3<INV>(a0, a1, a2); y[0] = a0; y[1] = a1; y[2] = a2; }
    { cplx a0 = x[1], a1 = x[3], a2 = x[5]; r3<INV>(a0, a1, a2);
      y[3] = a0; y[4] = cmulc(a1, w6k<INV>(1)); y[5] = cmulc(a2, w6k<INV>(2)); }
    #pragma unroll
    for (int q = 0; q < 3; ++q){
        cplx s = caddc(y[q], y[q+3]), d = csubc(y[q], y[q+3]);
        x[q] = s; x[q+3] = d;
    }
}

// ---------------------------------------------------------------------------
// K1: coil = csm*p, padded row FFT 96->288 via DIF 6x16, g stored fp16.
// ---------------------------------------------------------------------------
__global__ __launch_bounds__(512, 4)
void k_fwd(const cplx* __restrict__ pv, const cplx* __restrict__ csm,
           gpak* __restrict__ g, int cg0, int ncg, int ncga)
{
    __shared__ cplx A[NR * LSTR];
    const int tid = threadIdx.x, bid = blockIdx.x;
    const int tile = bid % TILES;
    const int rem = bid / TILES;
    const int gc = rem % ncg, b = rem / ncg, c = cg0 + gc;
    const int colbase = tile * TILE;
    const cplx* pp = pv  + (size_t)b * NVOX;
    const cplx* cs = csm + ((size_t)b * C_ + c) * NVOX;
    gpak* gg = g + (size_t)(b * ncga + gc) * ((size_t)NP * NCOL);

    for (int a = 0; a < 3; ++a){
        if (a) __syncthreads();
        #pragma unroll
        for (int it = 0; it < 2; ++it){
            const int id = tid + it * 512;
            if (id < 768){
                const int m = id / TILE, col = id - m * TILE;
                cplx xv[6];
                #pragma unroll
                for (int v = 0; v < 6; ++v){
                    const int gi = (m + 16*v) * NCOL + colbase + col;
                    xv[v] = cmulc(pp[gi], cs[gi]);
                }
                if (a){
                    cplx t = twf((float)(a*m), R288);
                    const cplx stp = twf((float)(16*a), R288);
                    #pragma unroll
                    for (int v = 0; v < 6; ++v){ xv[v] = cmulc(xv[v], t); t = cmulc(t, stp); }
                }
                dft6<false>(xv);
                cplx* dst = &A[m * LSTR + col];
                dst[0] = xv[0];
                const cplx w1 = twf((float)m, R96);
                cplx t = w1;
                #pragma unroll
                for (int r = 1; r < 6; ++r){ dst[16*r*LSTR] = cmulc(xv[r], t); t = cmulc(t, w1); }
            }
        }
        __syncthreads();
        if (tid < 288){
            const int r = tid / TILE, col = tid - r * TILE;
            cplx d[16];
            #pragma unroll
            for (int m = 0; m < 16; ++m) d[m] = A[(m + 16*r) * LSTR + col];
            dft16<false>(d);
            const cplx pref = twf((float)(32*a), R96);   // e^{-2pi i a/3}
            #pragma unroll
            for (int t = 0; t < 16; ++t)
                gg[(size_t)(18*t + 3*r + a) * NCOL + colbase + col] = pack_g(cmulc(d[t], pref));
        }
    }
}

// ---------------------------------------------------------------------------
// K2: per padded row: g <- conj(w) * IFFT2( pm * FFT2( w*g ) ), DIF->DIT,
// permuted mask, in-place passes, turnaround fused in registers; g fp16.
// ---------------------------------------------------------------------------
__global__ __launch_bounds__(512, 4)
void k_plane(gpak* __restrict__ g, const cplx* __restrict__ wpsf,
             const float* __restrict__ pm3, int ncg, int ncga)
{
    __shared__ cplx A[NC_ * LSTR];
    const int tid = threadIdx.x, bid = blockIdx.x;
    const int rp = bid % NP;
    const int rem = bid / NP;
    const int gc = rem % ncg, b = rem / ncg;
    gpak* gg = g + ((size_t)(b * ncga + gc) * NP + rp) * NCOL;
    const cplx*  wp  = wpsf + ((size_t)b * NP + rp) * NCOL;
    const float* pmv = pm3  + ((size_t)b * NP + rp) * NCOL;

    // ph1: ns DIF p1 (radix-3) from global, x w
    #pragma unroll
    for (int it = 0; it < 3; ++it){
        const int id = tid + it * 512;
        const int m = id & 15, nc = id >> 4;
        cplx xv[3];
        #pragma unroll
        for (int v = 0; v < 3; ++v){
            const int e = nc * NS + m + 16*v;
            xv[v] = cmulc(unpack_g(gg[e]), wp[e]);
        }
        r3<false>(xv[0], xv[1], xv[2]);
        cplx* dst = &A[nc * LSTR + m];
        const cplx w1 = twf((float)m, R48);
        dst[0]  = xv[0];
        dst[16] = cmulc(xv[1], w1);
        dst[32] = cmulc(xv[2], cmulc(w1, w1));
    }
    __syncthreads();
    // ph2: ns DIF p2 (radix-16, contiguous, in place)
    if (tid < 288){
        const int rho = tid / 96, nc = tid - rho * 96;
        cplx* pA = &A[nc * LSTR + 16 * rho];
        cplx d[16];
        #pragma unroll
        for (int m = 0; m < 16; ++m) d[m] = pA[m];
        dft16<false>(d);
        #pragma unroll
        for (int t = 0; t < 16; ++t) pA[t] = d[t];
    }
    __syncthreads();
    // ph3: nc DIF p1 (radix-6, in place)
    #pragma unroll
    for (int it = 0; it < 2; ++it){
        const int id = tid + it * 512;
        if (id < 768){
            const int m = id / NS, ns = id - m * NS;
            cplx xv[6];
            #pragma unroll
            for (int v = 0; v < 6; ++v) xv[v] = A[(m + 16*v) * LSTR + ns];
            dft6<false>(xv);
            const cplx w1 = twf((float)m, R96);
            A[m * LSTR + ns] = xv[0];
            cplx t = w1;
            #pragma unroll
            for (int r = 1; r < 6; ++r){ A[(m + 16*r) * LSTR + ns] = cmulc(xv[r], t); t = cmulc(t, w1); }
        }
    }
    __syncthreads();
    // ph4: nc DIF p2 + permuted mask + nc DIT p2 — in registers
    if (tid < 288){
        const int r = tid / NS, ns = tid - r * NS;
        cplx d[16];
        #pragma unroll
        for (int m = 0; m < 16; ++m) d[m] = A[(m + 16*r) * LSTR + ns];
        dft16<false>(d);
        #pragma unroll
        for (int t = 0; t < 16; ++t){
            const float mval = pmv[(6*t + r) * NS + ns];
            d[t].x *= mval; d[t].y *= mval;
        }
        dft16<true>(d);
        #pragma unroll
        for (int m = 0; m < 16; ++m) A[(m + 16*r) * LSTR + ns] = d[m];
    }
    __syncthreads();
    // ph5: nc DIT p1 (undo radix-6, in place)
    #pragma unroll
    for (int it = 0; it < 2; ++it){
        const int id = tid + it * 512;
        if (id < 768){
            const int m = id / NS, ns = id - m * NS;
            cplx xv[6];
            const cplx w1 = twf(-(float)m, R96);
            cplx t = make_float2(1.f, 0.f);
            #pragma unroll
            for (int r = 0; r < 6; ++r){ xv[r] = cmulc(A[(m + 16*r) * LSTR + ns], t); t = cmulc(t, w1); }
            dft6<true>(xv);
            #pragma unroll
            for (int v = 0; v < 6; ++v) A[(m + 16*v) * LSTR + ns] = xv[v];
        }
    }
    __syncthreads();
    // ph6: ns DIT p2 (idft16 contiguous, in place)
    if (tid < 288){
        const int rho = tid / 96, nc = tid - rho * 96;
        cplx* pA = &A[nc * LSTR + 16 * rho];
        cplx d[16];
        #pragma unroll
        for (int t = 0; t < 16; ++t) d[t] = pA[t];
        dft16<true>(d);
        #pragma unroll
        for (int m = 0; m < 16; ++m) pA[m] = d[m];
    }
    __syncthreads();
    // ph7: ns DIT p1 (undo radix-3) x conj(w), store fp16
    #pragma unroll
    for (int it = 0; it < 3; ++it){
        const int id = tid + it * 512;
        const int m = id & 15, nc = id >> 4;
        const cplx w1 = twf(-(float)m, R48);
        cplx xv[3];
        xv[0] = A[nc * LSTR + m];
        xv[1] = cmulc(A[nc * LSTR + m + 16], w1);
        xv[2] = cmulc(A[nc * LSTR + m + 32], cmulc(w1, w1));
        r3<true>(xv[0], xv[1], xv[2]);
        #pragma unroll
        for (int v = 0; v < 3; ++v){
            const int e = nc * NS + m + 16*v;
            gg[e] = pack_g(cmuljc(xv[v], wp[e]));
        }
    }
}

// ---------------------------------------------------------------------------
// K3: row IFFT 288->96 (crop) via DIT 16x6 per a-slice, 3 coils per block;
// conj(csm) folded into the accumulate; ONE atomic sweep per block into ap.
// ---------------------------------------------------------------------------
__global__ __launch_bounds__(512, 3)
void k_inv(const gpak* __restrict__ g, const cplx* __restrict__ csm,
           float* __restrict__ ap, int cg0, int ncg, int ng, int ncga)
{
    __shared__ cplx A[NR * LSTR];
    const int tid = threadIdx.x, bid = blockIdx.x;
    const int tile = bid % TILES;
    const int rem = bid / TILES;
    const int gl = rem % ng, b = rem / ng;
    const int cbase = cg0 + gl * CPB;
    const int cnum = (ncg - gl * CPB) < CPB ? (ncg - gl * CPB) : CPB;
    const int colbase = tile * TILE;

    cplx accT[2][6];
    #pragma unroll
    for (int it = 0; it < 2; ++it)
        #pragma unroll
        for (int j = 0; j < 6; ++j) accT[it][j] = make_float2(0.f, 0.f);

    bool first = true;
    for (int ci = 0; ci < cnum; ++ci){
        const int c = cbase + ci;
        const gpak* gc_ = g + (size_t)(b * ncga + (c - cg0)) * ((size_t)NP * NCOL);
        const cplx* cs  = csm + ((size_t)b * C_ + c) * NVOX;

        for (int a = 0; a < 3; ++a){
            if (!first) __syncthreads();
            first = false;
            // DIT p1: idft16 over decimated global gathers -> LDS
            if (tid < 288){
                const int c6 = tid / TILE, col = tid - c6 * TILE;
                cplx d[16];
                #pragma unroll
                for (int u = 0; u < 16; ++u)
                    d[u] = unpack_g(gc_[(size_t)(3*(c6 + 6*u) + a) * NCOL + colbase + col]);
                dft16<true>(d);
                #pragma unroll
                for (int q = 0; q < 16; ++q) A[(c6 + 6*q) * LSTR + col] = d[q];
            }
            __syncthreads();
            // DIT p2: x W96^{-cq}, idft6, fold f(a,y)/288 AND conj(csm), accumulate
            #pragma unroll
            for (int it = 0; it < 2; ++it){
                const int id = tid + it * 512;
                if (id < 768){
                    const int q = id / TILE, col = id - q * TILE;
                    cplx xv[6];
                    const cplx w1 = twf(-(float)q, R96);
                    cplx t = make_float2(1.f, 0.f);
                    #pragma unroll
                    for (int cc = 0; cc < 6; ++cc){ xv[cc] = cmulc(A[(cc + 6*q) * LSTR + col], t); t = cmulc(t, w1); }
                    dft6<true>(xv);
                    cplx f = twf(-(float)(a * (q + 96)), R288);
                    f.x *= (1.f/288.f); f.y *= (1.f/288.f);
                    const cplx fs = twf(-(float)(16 * a), R288);
                    #pragma unroll
                    for (int j = 0; j < 6; ++j){
                        const int gi = (q + 16*j) * NCOL + colbase + col;
                        accT[it][j] = caddc(accT[it][j], cmuljc(cmulc(xv[j], f), cs[gi]));
                        f = cmulc(f, fs);
                    }
                }
            }
        }
    }
    // single atomic epilogue
    float* apb = ap + (size_t)b * NVOX * 2;
    #pragma unroll
    for (int it = 0; it < 2; ++it){
        const int id = tid + it * 512;
        if (id < 768){
            const int q = id / TILE, col = id - q * TILE;
            #pragma unroll
            for (int j = 0; j < 6; ++j){
                const int gi = (q + 16*j) * NCOL + colbase + col;
                atomAddF(&apb[2 * gi],     accT[it][j].x);
                atomAddF(&apb[2 * gi + 1], accT[it][j].y);
            }
        }
    }
}

// ---------------------------------------------------------------------------
// permuted mask builder (once per solve)
// ---------------------------------------------------------------------------
__global__ __launch_bounds__(512)
void k_pmb(const float* __restrict__ mask, float* __restrict__ pm3)
{
    const int bid = blockIdx.x;            // b*NP + rp
    const float* mk = mask + (size_t)bid * NCOL;
    float* out = pm3 + (size_t)bid * NCOL;
    for (int e = threadIdx.x; e < NCOL; e += 512){
        const int knc = e / NS, pns = e - knc * NS;
        const int kns = 3 * (pns & 15) + (pns >> 4);
        out[e] = mk[knc * NS + kns] * (1.f / 4608.f);
    }
}

// ---------------------------------------------------------------------------
// CG kernels
// ---------------------------------------------------------------------------
__device__ inline float block_reduce_sum256(float v){
    #pragma unroll
    for (int o = 32; o >= 1; o >>= 1) v += __shfl_down(v, o, 64);
    __shared__ float sh[4];
    const int lane = threadIdx.x & 63, wv = threadIdx.x >> 6;
    if (lane == 0) sh[wv] = v;
    __syncthreads();
    float s = 0.f;
    if (threadIdx.x == 0) { s = sh[0] + sh[1] + sh[2] + sh[3]; }
    return s;
}

__global__ __launch_bounds__(256)
void k_rr0(const cplx* __restrict__ r, float* __restrict__ sc)
{
    const int i = blockIdx.x * 256 + threadIdx.x;
    const int b = i / NVOX;
    const cplx rv = r[i];
    const float s = block_reduce_sum256(rv.x*rv.x + rv.y*rv.y);
    if (threadIdx.x == 0) atomAddF(&sc[0 + b], s);
}

__global__ __launch_bounds__(256)
void k_dot(const cplx* __restrict__ p, const cplx* __restrict__ ap,
           const float* __restrict__ lam1, float* __restrict__ sc, int rn)
{
    const int i = blockIdx.x * 256 + threadIdx.x;
    const int b = i / NVOX;
    const float lam = lam1[0];
    const cplx pv = p[i];
    cplx a = ap[i];
    a.x += lam * pv.x; a.y += lam * pv.y;
    const float s = block_reduce_sum256(pv.x*a.x + pv.y*a.y);
    if (threadIdx.x == 0) atomAddF(&sc[4 + b], s);
    if (blockIdx.x == 0 && threadIdx.x < 2) sc[rn + threadIdx.x] = 0.f;
}

__global__ __launch_bounds__(256)
void k_update(cplx* __restrict__ x, cplx* __restrict__ r,
              const cplx* __restrict__ p, const cplx* __restrict__ ap,
              const float* __restrict__ lam1, float* __restrict__ sc, int rc, int rn)
{
    const int i = blockIdx.x * 256 + threadIdx.x;
    const int b = i / NVOX;
    const float rtr = sc[rc + b];
    const bool act = rtr > 1e-5f;
    const float alpha = rtr / sc[4 + b];
    const float lam = lam1[0];
    const cplx pv = p[i];
    cplx a = ap[i];
    a.x += lam * pv.x; a.y += lam * pv.y;
    cplx rv = r[i];
    if (act){
        cplx xv = x[i];
        xv.x += alpha * pv.x; xv.y += alpha * pv.y;
        x[i] = xv;
        rv.x -= alpha * a.x; rv.y -= alpha * a.y;
        r[i] = rv;
    }
    const float s = block_reduce_sum256(rv.x*rv.x + rv.y*rv.y);
    if (threadIdx.x == 0) atomAddF(&sc[rn + b], s);
}

__global__ __launch_bounds__(256)
void k_pupd(cplx* __restrict__ p, const cplx* __restrict__ r,
            float* __restrict__ sc, int rc, int rn)
{
    const int i = blockIdx.x * 256 + threadIdx.x;
    const int b = i / NVOX;
    const float rtr = sc[rc + b];
    if (rtr > 1e-5f){
        const float be = sc[rn + b] / rtr;
        const cplx pv = p[i], rv = r[i];
        p[i] = make_float2(rv.x + be * pv.x, rv.y + be * pv.y);
    }
    if (blockIdx.x == 0 && threadIdx.x < 2) sc[4 + threadIdx.x] = 0.f;
}

// ---------------------------------------------------------------------------
extern "C" void kernel_launch(void* const* d_in, const int* in_sizes, int n_in,
                              void* d_out, int out_size, void* d_ws, size_t ws_size,
                              hipStream_t stream)
{
    const cplx*  rhs  = (const cplx*)d_in[0];
    const cplx*  csm  = (const cplx*)d_in[1];
    const float* mask = (const float*)d_in[2];
    const cplx*  wpsf = (const cplx*)d_in[3];
    const float* lam1 = (const float*)d_in[4];

    const size_t vb  = (size_t)B_ * NVOX * sizeof(cplx);           // 7,077,888 B
    const size_t pmb = (size_t)B_ * NP * NCOL * sizeof(float);     // 10.6 MB
    const size_t percoil = (size_t)B_ * NP * NCOL * sizeof(gpak);  // 10.6 MB (fp16)

    char* ws = (char*)d_ws;
    float* sc = (float*)ws;
    size_t off = 256;
    cplx* r    = (cplx*)(ws + off); off += vb;
    cplx* p    = (cplx*)(ws + off); off += vb;
    float* pm3 = (float*)(ws + off); off += pmb;
    cplx* ap   = (cplx*)(ws + off); off += vb;
    gpak* g    = (gpak*)(ws + off);
    cplx* x    = (cplx*)d_out;

    int ncga = 3;
    if (ws_size > off){
        size_t fit = (ws_size - off) / percoil;
        ncga = fit > (size_t)C_ ? C_ : (int)fit;
        ncga -= ncga % CPB;
        if (ncga < CPB) ncga = CPB;
    }

    hipMemsetAsync(d_out, 0, vb, stream);
    hipMemsetAsync(sc, 0, 256, stream);
    hipMemcpyAsync(r, rhs, vb, hipMemcpyDeviceToDevice, stream);
    hipMemcpyAsync(p, rhs, vb, hipMemcpyDeviceToDevice, stream);
    k_pmb<<<B_ * NP, 512, 0, stream>>>(mask, pm3);
    k_rr0<<<(B_ * NVOX) / 256, 256, 0, stream>>>(r, sc);

    for (int it = 0; it < 10; ++it){
        hipMemsetAsync(ap, 0, vb, stream);
        for (int cg0 = 0; cg0 < C_; cg0 += ncga){
            const int ncg = (C_ - cg0 < ncga) ? (C_ - cg0) : ncga;
            const int ng = (ncg + CPB - 1) / CPB;
            k_fwd  <<<TILES * ncg * B_, 512, 0, stream>>>(p, csm, g, cg0, ncg, ncga);
            k_plane<<<NP    * ncg * B_, 512, 0, stream>>>(g, wpsf, pm3, ncg, ncga);
            k_inv  <<<TILES * ng  * B_, 512, 0, stream>>>(g, csm, (float*)ap, cg0, ncg, ng, ncga);
        }
        const int rc = (it & 1) ? 2 : 0, rn = 2 - rc;
        k_dot   <<<(B_ * NVOX) / 256, 256, 0, stream>>>(p, ap, lam1, sc, rn);
        k_update<<<(B_ * NVOX) / 256, 256, 0, stream>>>(x, r, p, ap, lam1, sc, rc, rn);
        k_pupd  <<<(B_ * NVOX) / 256, 256, 0, stream>>>(p, r, sc, rc, rn);
    }
}